// Round 8
// baseline (170.048 us; speedup 1.0000x reference)
//
#include <hip/hip_runtime.h>
#include <hip/hip_bf16.h>

#if defined(__has_builtin)
#if __has_builtin(__builtin_amdgcn_exp2f)
#define EXP2F __builtin_amdgcn_exp2f
#endif
#if __has_builtin(__builtin_amdgcn_rcpf)
#define RCPF __builtin_amdgcn_rcpf
#endif
#endif
#ifndef EXP2F
#define EXP2F exp2f
#endif
#ifndef RCPF
#define RCPF(x) (1.0f / (x))
#endif

// Sizes (fixed by the problem)
#define B_  8
#define Q_  256
#define K_  1024
#define D_  256
#define H_  128
#define DV_ 128

#define CSL 2.8853900817779268f   // 2*log2(e)
#define L2E 1.4426950408889634f   // log2(e)

// Workspace layout (floats). ~13.7 MB used. Harness poisons the whole d_ws
// (256 MiB fill ~42 us) + restores d_in (~18 us) every timed iter — fixed.
#define QE_OFF   0                // qE   [B*Q][H]              = 262144
#define KE_OFF   262144           // kET2 [B][64 p][K] float2   = 1048576
#define WPK_OFF  1310720          // wpk  [64] float4           = 256
#define AVP_OFF  1310976          // avpart [8 ks][2048][128]   = 2097152
#define SP_OFF   3408128          // spart  [8 ks][2048]        = 16384

// ---------------------------------------------------------------------------
// proj_kernel: 320 blocks, 64 rows x 64 cols, 256 threads, 4x4 micro-tile,
// all-b128 LDS reads. Epilogue exp2(CSL*x); Q -> qE row-major; K ->
// kET2[b][p][k] float2 = (E_{2p}, E_{2p+1}).
// ---------------------------------------------------------------------------
__global__ __launch_bounds__(256) void proj_kernel(
    const float* __restrict__ queries, const float* __restrict__ keys,
    const float* __restrict__ Wq, const float* __restrict__ Wk,
    const float* __restrict__ w_v,
    float* __restrict__ qE, float2* __restrict__ kET2, float* __restrict__ wpk)
{
    __shared__ __align__(16) float As[64][68];   // [d][row], pad 68
    __shared__ __align__(16) float Ws[64][64];   // [d][col]

    const int tid = threadIdx.x;
    const int blk = blockIdx.x;
    const bool isQ = blk < 64;
    const int t = isQ ? blk : (blk - 64);
    const int rowtile = t >> 1;
    const int cbase = (t & 1) * 64;
    const int row0 = rowtile * 64;
    const float* A = isQ ? (queries + row0 * D_) : (keys + row0 * D_);
    const float* W = isQ ? Wq : Wk;

    float acc[4][4];
#pragma unroll
    for (int i = 0; i < 4; i++)
#pragma unroll
        for (int j = 0; j < 4; j++) acc[i][j] = 0.f;

    const int lr  = tid & 63;          // A-stage row
    const int ldb = (tid >> 6) * 16;   // A-stage d base
    const int r4  = (tid >> 4) * 4;    // compute row base 0..60
    const int c4  = (tid & 15) * 4;    // compute col base 0..60

    for (int d0 = 0; d0 < D_; d0 += 64) {
#pragma unroll
        for (int j = 0; j < 4; j++) {
            const float4 a = *(const float4*)&A[lr * D_ + d0 + ldb + j * 4];
            As[ldb + j * 4 + 0][lr] = a.x;
            As[ldb + j * 4 + 1][lr] = a.y;
            As[ldb + j * 4 + 2][lr] = a.z;
            As[ldb + j * 4 + 3][lr] = a.w;
        }
#pragma unroll
        for (int l = 0; l < 4; l++) {
            const int idx = tid + l * 256;
            const int rr = idx >> 4, cc = (idx & 15) * 4;
            *(float4*)&Ws[rr][cc] = *(const float4*)&W[(d0 + rr) * H_ + cbase + cc];
        }
        __syncthreads();
#pragma unroll 4
        for (int d = 0; d < 64; d++) {
            const float4 a4 = *(const float4*)&As[d][r4];
            const float4 w4 = *(const float4*)&Ws[d][c4];
            const float ar[4] = {a4.x, a4.y, a4.z, a4.w};
#pragma unroll
            for (int i = 0; i < 4; i++) {
                acc[i][0] = fmaf(ar[i], w4.x, acc[i][0]);
                acc[i][1] = fmaf(ar[i], w4.y, acc[i][1]);
                acc[i][2] = fmaf(ar[i], w4.z, acc[i][2]);
                acc[i][3] = fmaf(ar[i], w4.w, acc[i][3]);
            }
        }
        __syncthreads();
    }

#pragma unroll
    for (int i = 0; i < 4; i++) {
        float e[4];
#pragma unroll
        for (int j = 0; j < 4; j++) e[j] = EXP2F(CSL * acc[i][j]);
        const int row = row0 + r4 + i;
        if (isQ) {
            *(float4*)&qE[row * H_ + cbase + c4] = make_float4(e[0], e[1], e[2], e[3]);
        } else {
            const int b = row >> 10, k = row & 1023;
            const int p0 = (cbase + c4) >> 1;
            kET2[(size_t)(b * 64 + p0) * K_ + k]     = make_float2(e[0], e[1]);
            kET2[(size_t)(b * 64 + p0 + 1) * K_ + k] = make_float2(e[2], e[3]);
        }
    }

    if (blk == 0 && tid < 64) {
        const float w1 = -2.0f * L2E * w_v[2 * tid];
        const float w2 = -2.0f * L2E * w_v[2 * tid + 1];
        *(float4*)&wpk[tid * 4] = make_float4(w1, w2, w1 + w2, 0.f);
    }
}

// ---------------------------------------------------------------------------
// attn_kernel: 2048 blocks x 256 threads. Block = (b=idx&7, ks=(idx>>3)&7,
// qt=idx>>6): 8 q-rows x 128 k. Masked blocks (ks*128 >= vl) return
// immediately; combine only reads parts with k0 < vl, so no zero-fill needed.
// Thread = (kl=tid&127, qh=tid>>7): 4 q-accumulators, 1 k.
// 8 blocks/CU = 32 waves/CU (round-7 fix: 4x the wave count, fine-grain
// interleave of (b,ks) for balance). kET2 amortized over 8 q-rows.
// h-pairing: w1/(1+x1)+w2/(1+x2) = [(w1+w2)+w1*x2+w2*x1]/[(1+x1)(1+x2)].
// ---------------------------------------------------------------------------
__global__ __launch_bounds__(256, 8) void attn_kernel(
    const float* __restrict__ qE,       // [B*Q][H] = e^{2q}
    const float2* __restrict__ kET2,    // [B][64][K] h-pairs of e^{2k}
    const float* __restrict__ values,   // [B][K][DV]
    const int*   __restrict__ valid_lens,
    const float* __restrict__ wpk,      // [64] float4 (w1,w2,w1+w2,0)
    float* __restrict__ avpart,         // [8][2048][128]
    float* __restrict__ spart)          // [8][2048]
{
    __shared__ float sc[8][128];        // [q][k-local] p-values, 4 KB
    __shared__ __align__(16) float psum[4][4];  // [wave][q-local]

    const int tid = threadIdx.x;
    const int idx = blockIdx.x;
    const int b  = idx & 7;
    const int ks = (idx >> 3) & 7;
    const int qt = idx >> 6;            // 0..31
    const int vl = valid_lens[b];
    const int k0 = ks * 128;
    if (k0 >= vl) return;               // masked part: combine won't read it

    const int q0 = qt * 8;
    const int kl = tid & 127;
    const int qh = tid >> 7;            // 0/1 -> q rows qh*4..+3
    const int k  = k0 + kl;
    const float* qp = qE + (b * Q_ + q0 + qh * 4) * H_;

    float acc[4] = {0.f, 0.f, 0.f, 0.f};

    if (k < vl) {
        const float2* kb = kET2 + (size_t)(b * 64) * K_ + k;
#pragma unroll 2
        for (int p = 0; p < 64; p++) {
            const float2 ek = kb[(size_t)p * K_];
            const float4 wp = *(const float4*)&wpk[p * 4];
#pragma unroll
            for (int q = 0; q < 4; q++) {
                const float2 qq = *(const float2*)&qp[q * H_ + 2 * p];
                const float x1 = qq.x * ek.x, x2 = qq.y * ek.y;
                const float e1 = x1 + 1.f;
                const float d  = fmaf(e1, x2, e1);
                float n = fmaf(wp.y, x1, wp.z);
                n = fmaf(wp.x, x2, n);
                acc[q] = fmaf(n, RCPF(d), acc[q]);
            }
        }
    }

    // ---- exp + mask; sc[q][kl]; partial row sums for this 128-k chunk ----
    const bool valid = k < vl;
    float p4[4];
#pragma unroll
    for (int q = 0; q < 4; q++) {
        p4[q] = valid ? EXP2F(acc[q]) : 0.f;
        sc[qh * 4 + q][kl] = p4[q];
    }
#pragma unroll
    for (int sh = 32; sh > 0; sh >>= 1) {
#pragma unroll
        for (int q = 0; q < 4; q++) p4[q] += __shfl_xor(p4[q], sh);
    }
    const int lane = tid & 63, w = tid >> 6;    // wave w: qh=w>>1, k-half=w&1
    if (lane == 0) *(float4*)&psum[w][0] = make_float4(p4[0], p4[1], p4[2], p4[3]);
    __syncthreads();
    if (tid < 8) {
        const int qh2 = tid >> 2, j = tid & 3;
        spart[ks * 2048 + b * Q_ + q0 + tid] =
            psum[2 * qh2][j] + psum[2 * qh2 + 1][j];
    }

    // ---- partial AV over this 128-k chunk: thread = (q=tid>>5, v4) ----
    const int v4 = (tid & 31) * 4;
    const int q  = tid >> 5;            // 0..7
    const float* vb = values + (size_t)b * (K_ * DV_) + (size_t)k0 * DV_ + v4;
    float av0 = 0.f, av1 = 0.f, av2 = 0.f, av3 = 0.f;
    const int rem = vl - k0;
    const int imax = rem > 128 ? 128 : rem;
#pragma unroll 2
    for (int i = 0; i < imax; i++) {
        const float4 vv = *(const float4*)&vb[i * DV_];
        const float pp = sc[q][i];
        av0 = fmaf(pp, vv.x, av0);
        av1 = fmaf(pp, vv.y, av1);
        av2 = fmaf(pp, vv.z, av2);
        av3 = fmaf(pp, vv.w, av3);
    }
    *(float4*)&avpart[(size_t)(ks * 2048 + b * Q_ + q0 + q) * DV_ + v4] =
        make_float4(av0, av1, av2, av3);
}

// ---------------------------------------------------------------------------
// combine_kernel: out[row][v] = sum_{g<ceil(vl/128)} avpart[g][row][v]
//                               * rcp(sum_g spart[g][row]).
// 256 blocks x 256 threads, one float4 per thread.
// ---------------------------------------------------------------------------
__global__ __launch_bounds__(256) void combine_kernel(
    const float* __restrict__ avpart, const float* __restrict__ spart,
    const int* __restrict__ valid_lens, float* __restrict__ out)
{
    const int t = blockIdx.x * 256 + threadIdx.x;   // 0..65535
    const int idx = t * 4;
    const int row = idx >> 7;                       // 0..2047
    const int b = row >> 8;
    const int vl = valid_lens[b];
    const int np = (vl + 127) >> 7;                 // 1..8 active parts

    float ax = 0.f, ay = 0.f, az = 0.f, aw = 0.f, s = 0.f;
    for (int g = 0; g < np; g++) {
        const float4 r = *(const float4*)&avpart[(size_t)g * 2048 * DV_ + idx];
        ax += r.x; ay += r.y; az += r.z; aw += r.w;
        s += spart[g * 2048 + row];
    }
    const float rr = RCPF(s);
    *(float4*)&out[idx] = make_float4(ax * rr, ay * rr, az * rr, aw * rr);
}

extern "C" void kernel_launch(void* const* d_in, const int* in_sizes, int n_in,
                              void* d_out, int out_size, void* d_ws, size_t ws_size,
                              hipStream_t stream) {
    const float* queries    = (const float*)d_in[0];  // [8,256,256]
    const float* keys       = (const float*)d_in[1];  // [8,1024,256]
    const float* values     = (const float*)d_in[2];  // [8,1024,128]
    const int*   valid_lens = (const int*)d_in[3];    // [8]
    const float* W_q        = (const float*)d_in[4];  // [256,128]
    const float* W_k        = (const float*)d_in[5];  // [256,128]
    const float* w_v        = (const float*)d_in[6];  // [128]
    float* out = (float*)d_out;

    float*  ws     = (float*)d_ws;
    float*  qE     = ws + QE_OFF;
    float2* kET2   = (float2*)(ws + KE_OFF);
    float*  wpk    = ws + WPK_OFF;
    float*  avpart = ws + AVP_OFF;
    float*  spart  = ws + SP_OFF;

    proj_kernel<<<320, 256, 0, stream>>>(queries, keys, W_q, W_k, w_v, qE, kET2, wpk);
    attn_kernel<<<2048, 256, 0, stream>>>(qE, kET2, values, valid_lens, wpk, avpart, spart);
    combine_kernel<<<256, 256, 0, stream>>>(avpart, spart, valid_lens, out);
}

// Round 9
// 152.339 us; speedup vs baseline: 1.1162x; 1.1162x over previous
//
#include <hip/hip_runtime.h>
#include <hip/hip_bf16.h>

#if defined(__has_builtin)
#if __has_builtin(__builtin_amdgcn_exp2f)
#define EXP2F __builtin_amdgcn_exp2f
#endif
#if __has_builtin(__builtin_amdgcn_rcpf)
#define RCPF __builtin_amdgcn_rcpf
#endif
#endif
#ifndef EXP2F
#define EXP2F exp2f
#endif
#ifndef RCPF
#define RCPF(x) (1.0f / (x))
#endif

// Sizes (fixed by the problem)
#define B_  8
#define Q_  256
#define K_  1024
#define D_  256
#define H_  128
#define DV_ 128

#define CSL 2.8853900817779268f   // 2*log2(e)
#define L2E 1.4426950408889634f   // log2(e)

// Workspace layout (floats). ~7.4 MB used.
#define QE_OFF   0                // qE   [B*Q][H]              = 262144
#define KE_OFF   262144           // kET2 [B][64 p][K] float2   = 1048576
#define WPK_OFF  1310720          // wpk  [64] float4           = 256
#define AVP_OFF  1310976          // avpart [2 kh][2048][128]   = 524288
#define SP_OFF   1835264          // spart  [2 kh][2048]        = 4096

// ---------------------------------------------------------------------------
// proj_kernel: unchanged from round 8 (stable, ~10 us, never in top-5).
// ---------------------------------------------------------------------------
__global__ __launch_bounds__(256) void proj_kernel(
    const float* __restrict__ queries, const float* __restrict__ keys,
    const float* __restrict__ Wq, const float* __restrict__ Wk,
    const float* __restrict__ w_v,
    float* __restrict__ qE, float2* __restrict__ kET2, float* __restrict__ wpk)
{
    __shared__ __align__(16) float As[64][68];   // [d][row], pad 68
    __shared__ __align__(16) float Ws[64][64];   // [d][col]

    const int tid = threadIdx.x;
    const int blk = blockIdx.x;
    const bool isQ = blk < 64;
    const int t = isQ ? blk : (blk - 64);
    const int rowtile = t >> 1;
    const int cbase = (t & 1) * 64;
    const int row0 = rowtile * 64;
    const float* A = isQ ? (queries + row0 * D_) : (keys + row0 * D_);
    const float* W = isQ ? Wq : Wk;

    float acc[4][4];
#pragma unroll
    for (int i = 0; i < 4; i++)
#pragma unroll
        for (int j = 0; j < 4; j++) acc[i][j] = 0.f;

    const int lr  = tid & 63;
    const int ldb = (tid >> 6) * 16;
    const int r4  = (tid >> 4) * 4;
    const int c4  = (tid & 15) * 4;

    for (int d0 = 0; d0 < D_; d0 += 64) {
#pragma unroll
        for (int j = 0; j < 4; j++) {
            const float4 a = *(const float4*)&A[lr * D_ + d0 + ldb + j * 4];
            As[ldb + j * 4 + 0][lr] = a.x;
            As[ldb + j * 4 + 1][lr] = a.y;
            As[ldb + j * 4 + 2][lr] = a.z;
            As[ldb + j * 4 + 3][lr] = a.w;
        }
#pragma unroll
        for (int l = 0; l < 4; l++) {
            const int idx = tid + l * 256;
            const int rr = idx >> 4, cc = (idx & 15) * 4;
            *(float4*)&Ws[rr][cc] = *(const float4*)&W[(d0 + rr) * H_ + cbase + cc];
        }
        __syncthreads();
#pragma unroll 4
        for (int d = 0; d < 64; d++) {
            const float4 a4 = *(const float4*)&As[d][r4];
            const float4 w4 = *(const float4*)&Ws[d][c4];
            const float ar[4] = {a4.x, a4.y, a4.z, a4.w};
#pragma unroll
            for (int i = 0; i < 4; i++) {
                acc[i][0] = fmaf(ar[i], w4.x, acc[i][0]);
                acc[i][1] = fmaf(ar[i], w4.y, acc[i][1]);
                acc[i][2] = fmaf(ar[i], w4.z, acc[i][2]);
                acc[i][3] = fmaf(ar[i], w4.w, acc[i][3]);
            }
        }
        __syncthreads();
    }

#pragma unroll
    for (int i = 0; i < 4; i++) {
        float e[4];
#pragma unroll
        for (int j = 0; j < 4; j++) e[j] = EXP2F(CSL * acc[i][j]);
        const int row = row0 + r4 + i;
        if (isQ) {
            *(float4*)&qE[row * H_ + cbase + c4] = make_float4(e[0], e[1], e[2], e[3]);
        } else {
            const int b = row >> 10, k = row & 1023;
            const int p0 = (cbase + c4) >> 1;
            kET2[(size_t)(b * 64 + p0) * K_ + k]     = make_float2(e[0], e[1]);
            kET2[(size_t)(b * 64 + p0 + 1) * K_ + k] = make_float2(e[2], e[3]);
        }
    }

    if (blk == 0 && tid < 64) {
        const float w1 = -2.0f * L2E * w_v[2 * tid];
        const float w2 = -2.0f * L2E * w_v[2 * tid + 1];
        *(float4*)&wpk[tid * 4] = make_float4(w1, w2, w1 + w2, 0.f);
    }
}

// ---------------------------------------------------------------------------
// attn_kernel: 512 blocks x 1024 threads (round-4 occupancy discipline:
// 2 blocks/CU = 32 waves/CU, NO whole-block early return). Block =
// (kh = raw>>8, j = raw&255 -> b = j&7, qt = j>>3): 8 q-rows x 512 k.
// Thread = (qh = tid>>9, kl = tid&511): 4 q-accs, 1 k. Wave-level mask skip
// only; fully-masked blocks still write zero partials (combine is uncond).
// q-rows + wpk staged in LDS (kills per-p scalar-load chains of r7/r8).
// kET2 amortized over 8 q-rows -> 128 MB L2/L3 traffic total.
// h-pairing: w1/(1+x1)+w2/(1+x2) = [(w1+w2)+w1*x2+w2*x1]/[(1+x1)(1+x2)].
// ---------------------------------------------------------------------------
__global__ __launch_bounds__(1024, 8) void attn_kernel(
    const float* __restrict__ qE,       // [B*Q][H] = e^{2q}
    const float2* __restrict__ kET2,    // [B][64][K] h-pairs of e^{2k}
    const float* __restrict__ values,   // [B][K][DV]
    const int*   __restrict__ valid_lens,
    const float* __restrict__ wpk,      // [64] float4 (w1,w2,w1+w2,0)
    float* __restrict__ avpart,         // [2][2048][128]
    float* __restrict__ spart)          // [2][2048]
{
    __shared__ __align__(16) float qs[8][128];       // 4 KB  staged q rows
    __shared__ __align__(16) float wps[64 * 4];      // 1 KB  staged wpk
    __shared__ float sc[8][512];                     // 16 KB p-values
    __shared__ __align__(16) float red[4][8][128];   // 16 KB AV k-split
    __shared__ __align__(16) float psum[8][8];       // [kc][q]

    const int tid = threadIdx.x;
    const int raw = blockIdx.x;
    const int kh  = raw >> 8;            // k-half 0/1
    const int j   = raw & 255;
    const int b   = j & 7;               // consecutive blocks -> different b
    const int qt  = j >> 3;              // 0..31
    const int q0  = qt * 8;
    const int vl  = valid_lens[b];

    // stage q rows (8x128) and wpk into LDS
    qs[tid >> 7][tid & 127] = qE[(b * Q_ + q0 + (tid >> 7)) * H_ + (tid & 127)];
    if (tid < 256) wps[tid] = wpk[tid];
    __syncthreads();

    const int qh = tid >> 9;             // 0/1 -> q rows qh*4..+3
    const int kl = tid & 511;
    const int k  = kh * 512 + kl;

    float acc[4] = {0.f, 0.f, 0.f, 0.f};

    if (k < vl) {                        // wave-uniform in 64-lane chunks
        const float2* kb = kET2 + (size_t)(b * 64) * K_ + k;
        const float* qb = &qs[qh * 4][0];
#pragma unroll 4
        for (int p = 0; p < 64; p++) {
            const float2 ek = kb[(size_t)p * K_];
            const float4 wp = *(const float4*)&wps[p * 4];
#pragma unroll
            for (int q = 0; q < 4; q++) {
                const float2 qq = *(const float2*)&qb[q * 128 + 2 * p];
                const float x1 = qq.x * ek.x, x2 = qq.y * ek.y;
                const float e1 = x1 + 1.f;
                const float d  = fmaf(e1, x2, e1);
                float n = fmaf(wp.y, x1, wp.z);
                n = fmaf(wp.x, x2, n);
                acc[q] = fmaf(n, RCPF(d), acc[q]);
            }
        }
    }

    // ---- exp + mask; sc[q][kl]; per-wave partial row sums ----
    const bool valid = k < vl;
    float p4[4];
#pragma unroll
    for (int q = 0; q < 4; q++) {
        p4[q] = valid ? EXP2F(acc[q]) : 0.f;
        sc[qh * 4 + q][kl] = p4[q];
    }
#pragma unroll
    for (int sh = 32; sh > 0; sh >>= 1) {
#pragma unroll
        for (int q = 0; q < 4; q++) p4[q] += __shfl_xor(p4[q], sh);
    }
    const int lane = tid & 63, w = tid >> 6;   // wave: qh=w>>3, kc=w&7
    if (lane == 0)
        *(float4*)&psum[w & 7][(w >> 3) * 4] = make_float4(p4[0], p4[1], p4[2], p4[3]);
    __syncthreads();
    if (tid < 8) {
        float s = 0.f;
#pragma unroll
        for (int kc = 0; kc < 8; kc++) s += psum[kc][tid];
        spart[kh * 2048 + b * Q_ + q0 + tid] = s;
    }

    // ---- partial AV over this 512-k half: thread = (q=tid>>7, ks, v4) ----
    const int v4 = (tid & 31) * 4;
    const int ks = (tid >> 5) & 3;       // 4-way split of 512 k
    const int q  = tid >> 7;             // 0..7
    const int kb0 = kh * 512 + ks * 128;
    const float* vb = values + (size_t)b * (K_ * DV_) + (size_t)kb0 * DV_ + v4;
    float av0 = 0.f, av1 = 0.f, av2 = 0.f, av3 = 0.f;
    const int rem = vl - kb0;
    const int imax = rem <= 0 ? 0 : (rem > 128 ? 128 : rem);
#pragma unroll 2
    for (int i = 0; i < imax; i++) {
        const float4 vv = *(const float4*)&vb[i * DV_];
        const float pp = sc[q][ks * 128 + i];
        av0 = fmaf(pp, vv.x, av0);
        av1 = fmaf(pp, vv.y, av1);
        av2 = fmaf(pp, vv.z, av2);
        av3 = fmaf(pp, vv.w, av3);
    }
    *(float4*)&red[ks][q][v4] = make_float4(av0, av1, av2, av3);
    __syncthreads();

    {   // reduce 4-way k-split: all 1024 threads, one output each
        const int qq = tid >> 7, v = tid & 127;
        const float s = red[0][qq][v] + red[1][qq][v] + red[2][qq][v] + red[3][qq][v];
        avpart[(size_t)(kh * 2048 + b * Q_ + q0 + qq) * DV_ + v] = s;
    }
}

// ---------------------------------------------------------------------------
// combine_kernel: out = (av0+av1) * rcp(s0+s1). 256 blocks x 256 threads.
// Fully-masked kh=1 halves wrote zeros, so unconditional sum is exact.
// ---------------------------------------------------------------------------
__global__ __launch_bounds__(256) void combine_kernel(
    const float* __restrict__ avpart, const float* __restrict__ spart,
    float* __restrict__ out)
{
    const int idx = (blockIdx.x * 256 + threadIdx.x) * 4;   // 0..262140
    const int row = idx >> 7;
    const float4 a0 = *(const float4*)&avpart[idx];
    const float4 a1 = *(const float4*)&avpart[2048 * DV_ + idx];
    const float r = RCPF(spart[row] + spart[2048 + row]);
    *(float4*)&out[idx] = make_float4((a0.x + a1.x) * r, (a0.y + a1.y) * r,
                                      (a0.z + a1.z) * r, (a0.w + a1.w) * r);
}

extern "C" void kernel_launch(void* const* d_in, const int* in_sizes, int n_in,
                              void* d_out, int out_size, void* d_ws, size_t ws_size,
                              hipStream_t stream) {
    const float* queries    = (const float*)d_in[0];  // [8,256,256]
    const float* keys       = (const float*)d_in[1];  // [8,1024,256]
    const float* values     = (const float*)d_in[2];  // [8,1024,128]
    const int*   valid_lens = (const int*)d_in[3];    // [8]
    const float* W_q        = (const float*)d_in[4];  // [256,128]
    const float* W_k        = (const float*)d_in[5];  // [256,128]
    const float* w_v        = (const float*)d_in[6];  // [128]
    float* out = (float*)d_out;

    float*  ws     = (float*)d_ws;
    float*  qE     = ws + QE_OFF;
    float2* kET2   = (float2*)(ws + KE_OFF);
    float*  wpk    = ws + WPK_OFF;
    float*  avpart = ws + AVP_OFF;
    float*  spart  = ws + SP_OFF;

    proj_kernel<<<320, 256, 0, stream>>>(queries, keys, W_q, W_k, w_v, qE, kET2, wpk);
    attn_kernel<<<512, 1024, 0, stream>>>(qE, kET2, values, valid_lens, wpk, avpart, spart);
    combine_kernel<<<256, 256, 0, stream>>>(avpart, spart, out);
}